// Round 5
// baseline (232.422 us; speedup 1.0000x reference)
//
#include <hip/hip_runtime.h>

#define TT 128
#define CC 512
#define HIDN 1024
#define HORN 96
#define NB 256
#define BM 128     // t per block
#define BN 256     // h per block
#define BK 32      // k per stage
#define NSTAGE 16

typedef _Float16 f16x8 __attribute__((ext_vector_type(8)));
typedef _Float16 f16x4 __attribute__((ext_vector_type(4)));
typedef float f32x16 __attribute__((ext_vector_type(16)));

// LDS: two staging buffers [ x:16KB (f32 [128][32], 128B rows) | W:32KB ([256][hi64|lo64]) ]
// = 96 KB total; scan overlays the first 64 KB after the K-loop.
#define BUFSZ 49152
#define WOFF  16384
#define SMEM_BYTES 98304

// fp16 two-term split: v = hi + lo, |err| ~ 2^-22 * |v|
__device__ __forceinline__ void cvt_split(const float4 v, f16x4* hi, f16x4* lo) {
    auto h01 = __builtin_amdgcn_cvt_pkrtz(v.x, v.y);
    auto h23 = __builtin_amdgcn_cvt_pkrtz(v.z, v.w);
    auto l01 = __builtin_amdgcn_cvt_pkrtz(v.x - (float)h01.x, v.y - (float)h01.y);
    auto l23 = __builtin_amdgcn_cvt_pkrtz(v.z - (float)h23.x, v.w - (float)h23.y);
    *hi = (f16x4){(_Float16)h01.x, (_Float16)h01.y, (_Float16)h23.x, (_Float16)h23.y};
    *lo = (f16x4){(_Float16)l01.x, (_Float16)l01.y, (_Float16)l23.x, (_Float16)l23.y};
}

// f32x8 (two float4) -> hi/lo f16x8, same math as cvt_split (bit-identical products)
__device__ __forceinline__ void cvt_split8(const float4 f0, const float4 f1,
                                           f16x8* hi, f16x8* lo) {
    auto h0 = __builtin_amdgcn_cvt_pkrtz(f0.x, f0.y);
    auto h1 = __builtin_amdgcn_cvt_pkrtz(f0.z, f0.w);
    auto h2 = __builtin_amdgcn_cvt_pkrtz(f1.x, f1.y);
    auto h3 = __builtin_amdgcn_cvt_pkrtz(f1.z, f1.w);
    auto l0 = __builtin_amdgcn_cvt_pkrtz(f0.x - (float)h0.x, f0.y - (float)h0.y);
    auto l1 = __builtin_amdgcn_cvt_pkrtz(f0.z - (float)h1.x, f0.w - (float)h1.y);
    auto l2 = __builtin_amdgcn_cvt_pkrtz(f1.x - (float)h2.x, f1.y - (float)h2.y);
    auto l3 = __builtin_amdgcn_cvt_pkrtz(f1.z - (float)h3.x, f1.w - (float)h3.y);
    *hi = (f16x8){(_Float16)h0.x, (_Float16)h0.y, (_Float16)h1.x, (_Float16)h1.y,
                  (_Float16)h2.x, (_Float16)h2.y, (_Float16)h3.x, (_Float16)h3.y};
    *lo = (f16x8){(_Float16)l0.x, (_Float16)l0.y, (_Float16)l1.x, (_Float16)l1.y,
                  (_Float16)l2.x, (_Float16)l2.y, (_Float16)l3.x, (_Float16)l3.y};
}

__device__ __forceinline__ void gload16(const void* g, void* l) {
    __builtin_amdgcn_global_load_lds(
        (const __attribute__((address_space(1))) unsigned int*)g,
        (__attribute__((address_space(3))) unsigned int*)l, 16, 0, 0);
}

// Prologue: split W1 f32 -> whi/wlo f16 (once), and init out[b,o] = bh[o]
__global__ void __launch_bounds__(256)
snn_cvtw(const float* __restrict__ W1, f16x4* __restrict__ whi, f16x4* __restrict__ wlo,
         const float* __restrict__ bh, float* __restrict__ out)
{
    const int i = blockIdx.x * 256 + threadIdx.x;   // float4 index, 131072 total
    const float4 v = ((const float4*)W1)[i];
    f16x4 hi, lo;
    cvt_split(v, &hi, &lo);
    whi[i] = hi;
    wlo[i] = lo;
    if (i < NB * HORN) out[i] = bh[i % HORN];
}

// Fused proj GEMM (split-f16 MFMA, x staged as f32 via global_load_lds,
// single-raw-barrier double-buffered pipeline) + leaky scan -> memT[b,h]
// grid = 1024 (XCD-grouped: 4 h-tiles x 256 b), block = 512 (8 waves, 2x4)
__global__ void __launch_bounds__(512, 1)
snn_proj_scan(const float* __restrict__ x, const _Float16* __restrict__ whi_g,
              const _Float16* __restrict__ wlo_g, const float* __restrict__ b1,
              const float* __restrict__ betap, float* __restrict__ memT)
{
    __shared__ __align__(16) char smem[SMEM_BYTES];

    const int tid  = threadIdx.x;
    const int lane = tid & 63;
    const int wid  = tid >> 6;                  // 0..7
    const int wm = wid >> 2, wn = wid & 3;      // wave tile: 64t x 64h
    const int g2 = lane >> 5, lr = lane & 31;
    const int am = lr & 7;                      // 8-slot swizzle mask (row&7 == lr&7)

    // XCD grouping: bijective; 8 groups x (32 b x 4 h-tiles, h-consecutive share b)
    const int lid = blockIdx.x;
    const int idx = lid >> 3;
    const int b     = ((lid & 7) << 5) + (idx >> 2);
    const int hbase = (idx & 3) * BN;

    // ---- staging source pointers (pre-swizzled per-lane global, linear LDS dest) ----
    // chunk = 1 KB = 8 rows x 8 slots(16B); lane l -> row rr=l>>3, slot pp=l&7;
    // LDS[row][pp] must hold logical slot uu = pp ^ (row&7); row&7 == rr for all chunks.
    const int rr = lane >> 3, pp = lane & 7;
    const int uu = pp ^ rr;
    const char* xgc = (const char*)(x + (size_t)b * TT * CC);
    // x chunks 2wid, 2wid+1 (rows 16wid.., G row stride 2048 B, stage step 128 B)
    const char* xsrc0 = xgc + (size_t)(16 * wid + rr) * 2048 + uu * 16;
    const char* xsrc1 = xgc + (size_t)(16 * wid + 8 + rr) * 2048 + uu * 16;
    // W chunks 4wid..4wid+3: LDS rows [h][hi 64B | lo 64B]; logical slot<4 -> hi else lo
    const char* wbase = (uu < 4) ? (const char*)whi_g : (const char*)wlo_g;
    const char* wsrc0 = wbase + (size_t)(hbase + 32 * wid + rr) * 1024 + (uu & 3) * 16;
    const char* wsrc1 = wsrc0 + 8 * 1024;
    const char* wsrc2 = wsrc0 + 16 * 1024;
    const char* wsrc3 = wsrc0 + 24 * 1024;

    // fragment row bases (byte offsets within a buffer)
    const int arow0 = (wm * 64 + lr) * 128;         // x f32 rows, 128 B
    const int arow1 = arow0 + 32 * 128;
    const int brow0 = WOFF + (wn * 64 + lr) * 128;  // W f16 rows, 128 B (hi|lo)
    const int brow1 = brow0 + 32 * 128;

    f32x16 acc00 = {}, acc01 = {}, acc10 = {}, acc11 = {};

#define STAGE_LOADS(S, BB) { \
        gload16(xsrc0 + (S) * 128, smem + (BB) + (2 * wid) * 1024); \
        gload16(xsrc1 + (S) * 128, smem + (BB) + (2 * wid + 1) * 1024); \
        gload16(wsrc0 + (S) * 64,  smem + (BB) + WOFF + (4 * wid) * 1024); \
        gload16(wsrc1 + (S) * 64,  smem + (BB) + WOFF + (4 * wid + 1) * 1024); \
        gload16(wsrc2 + (S) * 64,  smem + (BB) + WOFF + (4 * wid + 2) * 1024); \
        gload16(wsrc3 + (S) * 64,  smem + (BB) + WOFF + (4 * wid + 3) * 1024); }

// one K=16 slice: read f32 A frags (swizzled), split in-reg, read f16 B frags, 12 MFMA.
// Per-acc product order hh, hl, lh identical to rounds 2-4 -> bit-identical output.
#define KSTEP(CUR, KS) { \
        const int ua16 = (((KS) * 4 + g2 * 2) ^ am) << 4; \
        const int ub16 = (((KS) * 2 + g2) ^ am) << 4; \
        const float4 a00 = *(const float4*)(smem + (CUR) + arow0 + ua16); \
        const float4 a01 = *(const float4*)(smem + (CUR) + arow0 + (ua16 ^ 16)); \
        const float4 a10 = *(const float4*)(smem + (CUR) + arow1 + ua16); \
        const float4 a11 = *(const float4*)(smem + (CUR) + arow1 + (ua16 ^ 16)); \
        const f16x8 bh0 = *(const f16x8*)(smem + (CUR) + brow0 + ub16); \
        const f16x8 bl0 = *(const f16x8*)(smem + (CUR) + brow0 + (ub16 ^ 64)); \
        const f16x8 bh1 = *(const f16x8*)(smem + (CUR) + brow1 + ub16); \
        const f16x8 bl1 = *(const f16x8*)(smem + (CUR) + brow1 + (ub16 ^ 64)); \
        f16x8 ah0, al0, ah1, al1; \
        cvt_split8(a00, a01, &ah0, &al0); \
        cvt_split8(a10, a11, &ah1, &al1); \
        acc00 = __builtin_amdgcn_mfma_f32_32x32x16_f16(ah0, bh0, acc00, 0, 0, 0); \
        acc01 = __builtin_amdgcn_mfma_f32_32x32x16_f16(ah0, bh1, acc01, 0, 0, 0); \
        acc10 = __builtin_amdgcn_mfma_f32_32x32x16_f16(ah1, bh0, acc10, 0, 0, 0); \
        acc11 = __builtin_amdgcn_mfma_f32_32x32x16_f16(ah1, bh1, acc11, 0, 0, 0); \
        acc00 = __builtin_amdgcn_mfma_f32_32x32x16_f16(ah0, bl0, acc00, 0, 0, 0); \
        acc01 = __builtin_amdgcn_mfma_f32_32x32x16_f16(ah0, bl1, acc01, 0, 0, 0); \
        acc10 = __builtin_amdgcn_mfma_f32_32x32x16_f16(ah1, bl0, acc10, 0, 0, 0); \
        acc11 = __builtin_amdgcn_mfma_f32_32x32x16_f16(ah1, bl1, acc11, 0, 0, 0); \
        acc00 = __builtin_amdgcn_mfma_f32_32x32x16_f16(al0, bh0, acc00, 0, 0, 0); \
        acc01 = __builtin_amdgcn_mfma_f32_32x32x16_f16(al0, bh1, acc01, 0, 0, 0); \
        acc10 = __builtin_amdgcn_mfma_f32_32x32x16_f16(al1, bh0, acc10, 0, 0, 0); \
        acc11 = __builtin_amdgcn_mfma_f32_32x32x16_f16(al1, bh1, acc11, 0, 0, 0); }

    // prologue: stage 0 into buf0
    STAGE_LOADS(0, 0)
    asm volatile("s_waitcnt vmcnt(0)" ::: "memory");
    __builtin_amdgcn_s_barrier();

#pragma unroll
    for (int s = 0; s < NSTAGE; ++s) {
        const int cur = (s & 1) ? BUFSZ : 0;
        const int nxt = (s & 1) ? 0 : BUFSZ;
        if (s + 1 < NSTAGE) STAGE_LOADS(s + 1, nxt)
        __builtin_amdgcn_sched_barrier(0);
        __builtin_amdgcn_s_setprio(1);
        KSTEP(cur, 0)
        KSTEP(cur, 1)
        __builtin_amdgcn_s_setprio(0);
        // gloads for nxt were issued a full stage ago -> drain is ~free; no lgkm drain
        asm volatile("s_waitcnt vmcnt(0)" ::: "memory");
        __builtin_amdgcn_s_barrier();
    }
#undef KSTEP
#undef STAGE_LOADS

    // ---- epilogue + scan, two 128-h halves over a 64 KB [128][128]f32 buffer ----
    // C/D layout: col = lane&31 (h), row t = (reg&3) + 8*(reg>>2) + 4*g2 (+32a+64wm)
#define ST_ACC(A, a, bb, wl) { \
        const int row = (wl) * 64 + (bb) * 32 + lr; \
        const int sb  = wm * 16 + (a) * 8 + g2; \
        const int rs  = row & 31; \
        char* rb = smem + row * 512; \
        *(float4*)(rb + (((sb + 0) ^ rs) * 16)) = make_float4(A[0],  A[1],  A[2],  A[3]);  \
        *(float4*)(rb + (((sb + 2) ^ rs) * 16)) = make_float4(A[4],  A[5],  A[6],  A[7]);  \
        *(float4*)(rb + (((sb + 4) ^ rs) * 16)) = make_float4(A[8],  A[9],  A[10], A[11]); \
        *(float4*)(rb + (((sb + 6) ^ rs) * 16)) = make_float4(A[12], A[13], A[14], A[15]); }

    const float beta_c = fminf(fmaxf(betap[0], 0.0f), 1.0f);

#pragma unroll
    for (int half = 0; half < 2; ++half) {
        if ((wn >> 1) == half) {
            const int wl = wn & 1;
            ST_ACC(acc00, 0, 0, wl)
            ST_ACC(acc01, 0, 1, wl)
            ST_ACC(acc10, 1, 0, wl)
            ST_ACC(acc11, 1, 1, wl)
        }
        __syncthreads();
        if (tid < 128) {
            const int hg = hbase + half * 128 + tid;
            const float b1h = b1[hg];
            const char* rb = smem + tid * 512;
            const int rs = tid & 31;
            float mem = 0.0f;
#pragma unroll
            for (int q = 0; q < 32; ++q) {
                const float4 v = *(const float4*)(rb + ((q ^ rs) * 16));
                float reset;
                reset = (mem > 1.0f) ? 1.0f : 0.0f; mem = beta_c * mem + (v.x + b1h) - reset;
                reset = (mem > 1.0f) ? 1.0f : 0.0f; mem = beta_c * mem + (v.y + b1h) - reset;
                reset = (mem > 1.0f) ? 1.0f : 0.0f; mem = beta_c * mem + (v.z + b1h) - reset;
                reset = (mem > 1.0f) ? 1.0f : 0.0f; mem = beta_c * mem + (v.w + b1h) - reset;
            }
            memT[(size_t)b * HIDN + hg] = mem;
        }
        __syncthreads();   // protect buffer reuse for the second half
    }
#undef ST_ACC
}

// Head: out[b,o] += memT[b, kc*64 : +64] . Wh[o, same] (bias pre-stored by cvtw)
// grid = (16 kchunks, 16 bgroups), block 256.
__global__ void __launch_bounds__(256)
snn_head(const float* __restrict__ memT, const float* __restrict__ Wh,
         float* __restrict__ out)
{
    __shared__ __align__(16) float ms[16][64];
    __shared__ __align__(16) float ws[HORN][64];
    const int tid = threadIdx.x;
    const int kc = blockIdx.x, bg = blockIdx.y;
    const int kof = kc * 64;

    {
        const int row = tid >> 4, c4 = tid & 15;
        *(float4*)&ms[row][c4 * 4] =
            *(const float4*)(memT + (size_t)(bg * 16 + row) * HIDN + kof + c4 * 4);
    }
#pragma unroll
    for (int r = 0; r < 6; ++r) {
        const int q = r * 256 + tid;
        const int row = q >> 4, c4 = q & 15;
        *(float4*)&ws[row][c4 * 4] =
            *(const float4*)(Wh + (size_t)row * HIDN + kof + c4 * 4);
    }
    __syncthreads();

#pragma unroll
    for (int r = 0; r < 6; ++r) {
        const int p = r * 256 + tid;
        const int bb = p / HORN, o = p % HORN;
        const float4* mv = (const float4*)&ms[bb][0];
        const float4* wv = (const float4*)&ws[o][0];
        float a = 0.0f;
#pragma unroll
        for (int q = 0; q < 16; ++q) {
            const float4 w = wv[q];
            const float4 m = mv[q];
            a = fmaf(w.x, m.x, fmaf(w.y, m.y, fmaf(w.z, m.z, fmaf(w.w, m.w, a))));
        }
        atomicAdd(out + (size_t)(bg * 16 + bb) * HORN + o, a);
    }
}

extern "C" void kernel_launch(void* const* d_in, const int* in_sizes, int n_in,
                              void* d_out, int out_size, void* d_ws, size_t ws_size,
                              hipStream_t stream)
{
    (void)in_sizes; (void)n_in; (void)out_size; (void)ws_size;
    const float* x    = (const float*)d_in[0];
    const float* W1   = (const float*)d_in[1];
    const float* b1   = (const float*)d_in[2];
    const float* Wh   = (const float*)d_in[3];
    const float* bh   = (const float*)d_in[4];
    const float* beta = (const float*)d_in[5];

    // ws layout: whi [1 MB] | wlo [1 MB] | memT [1 MB]
    char* ws = (char*)d_ws;
    _Float16* whi  = (_Float16*)(ws);
    _Float16* wlo  = (_Float16*)(ws + (1 << 20));
    float*    memT = (float*)(ws + (2 << 20));
    float*    out  = (float*)d_out;

    snn_cvtw<<<512, 256, 0, stream>>>(W1, (f16x4*)whi, (f16x4*)wlo, bh, out);
    snn_proj_scan<<<1024, 512, 0, stream>>>(x, whi, wlo, b1, beta, memT);
    snn_head<<<dim3(16, 16), 256, 0, stream>>>(memT, Wh, out);
}